// Round 1
// baseline (459.158 us; speedup 1.0000x reference)
//
#include <hip/hip_runtime.h>
#include <cstddef>

// Problem constants (from reference setup_inputs)
#define T_DIM 500
#define B_DIM 32
#define C_DIM 1024
#define O_DIM 1024
#define M_DIM (T_DIM * B_DIM)   // 16000
#define BO_DIM (B_DIM * O_DIM)  // 32768

// ---------------------------------------------------------------------------
// K0: transpose x[B, C, T] (fp32) -> xt[(t*B + b), c]  (row-major [M, C])
// LDS 32x32 tile transpose per b.
// ---------------------------------------------------------------------------
__global__ __launch_bounds__(256) void k_transpose(const float* __restrict__ x,
                                                   float* __restrict__ xt) {
  __shared__ float tile[32][33];
  const int b  = blockIdx.z;
  const int t0 = blockIdx.x * 32;
  const int c0 = blockIdx.y * 32;
  const int tx = threadIdx.x;      // 0..31
  const int ty = threadIdx.y;      // 0..7

  const int t = t0 + tx;
  if (t < T_DIM) {
#pragma unroll
    for (int r = 0; r < 4; ++r) {
      const int c = c0 + ty + r * 8;
      tile[ty + r * 8][tx] = x[((size_t)b * C_DIM + c) * T_DIM + t];
    }
  }
  __syncthreads();
#pragma unroll
  for (int r = 0; r < 4; ++r) {
    const int tt = t0 + ty + r * 8;
    if (tt < T_DIM) {
      xt[((size_t)tt * B_DIM + b) * C_DIM + c0 + tx] = tile[tx][ty + r * 8];
    }
  }
}

// ---------------------------------------------------------------------------
// K1: fp32 GEMM (NT):  C[M, O] = A[M, K] * W[O, K]^T
// 64x64 block tile, K-step 16, 256 threads, 4x4 per-thread microtile.
// ---------------------------------------------------------------------------
__global__ __launch_bounds__(256) void k_gemm(const float* __restrict__ A,
                                              const float* __restrict__ Bw,
                                              float* __restrict__ C) {
  __shared__ float As[16][68];  // [k][m], +4 pad: 16B-aligned rows, <=2-way bank alias
  __shared__ float Bs[16][68];  // [k][n]

  const int tid  = threadIdx.x;
  const int row0 = blockIdx.y * 64;   // M tile
  const int col0 = blockIdx.x * 64;   // N tile (fast grid dim -> W stays L2-hot)
  const int lrow = tid >> 2;          // 0..63 : tile row loaded by this thread
  const int lk4  = (tid & 3) << 2;    // 0,4,8,12 : K offset (float4)
  const int tx   = tid & 15;          // n-dir
  const int ty   = tid >> 4;          // m-dir (0..15)

  float acc[4][4] = {};

  const float* Aptr = A + (size_t)(row0 + lrow) * C_DIM + lk4;
  const float* Bptr = Bw + (size_t)(col0 + lrow) * C_DIM + lk4;

  for (int k0 = 0; k0 < C_DIM; k0 += 16) {
    const float4 av = *(const float4*)(Aptr + k0);
    const float4 bv = *(const float4*)(Bptr + k0);
    __syncthreads();  // previous iteration's LDS reads complete
    As[lk4 + 0][lrow] = av.x;
    As[lk4 + 1][lrow] = av.y;
    As[lk4 + 2][lrow] = av.z;
    As[lk4 + 3][lrow] = av.w;
    Bs[lk4 + 0][lrow] = bv.x;
    Bs[lk4 + 1][lrow] = bv.y;
    Bs[lk4 + 2][lrow] = bv.z;
    Bs[lk4 + 3][lrow] = bv.w;
    __syncthreads();
#pragma unroll
    for (int kk = 0; kk < 16; ++kk) {
      const float4 a4 = *(const float4*)&As[kk][ty * 4];
      const float4 b4 = *(const float4*)&Bs[kk][tx * 4];
      const float a[4] = {a4.x, a4.y, a4.z, a4.w};
      const float b[4] = {b4.x, b4.y, b4.z, b4.w};
#pragma unroll
      for (int i = 0; i < 4; ++i)
#pragma unroll
        for (int j = 0; j < 4; ++j) acc[i][j] += a[i] * b[j];
    }
  }

#pragma unroll
  for (int i = 0; i < 4; ++i) {
    const float4 r = make_float4(acc[i][0], acc[i][1], acc[i][2], acc[i][3]);
    *(float4*)&C[(size_t)(row0 + ty * 4 + i) * O_DIM + col0 + tx * 4] = r;
  }
}

// ---------------------------------------------------------------------------
// K2: fused PSP alpha-filter (linear, commutes with the GEMM) + refractory
// spike scan. One thread per (b, o) pair; sequential over T.
// v layout: v[t * BO + b*O + o]  (coalesced read each step)
// out layout: out[(b*O + o) * T + t]  (per-thread contiguous row, float4)
// ---------------------------------------------------------------------------
__global__ __launch_bounds__(256) void k_scan(const float* __restrict__ v,
                                              float* __restrict__ out) {
  const int g = blockIdx.x * 256 + threadIdx.x;  // b*O + o

  // fp64-accurate constants, cast to fp32 (matches reference np.exp -> float32)
  const float a1 = 0.90483741803595952f;   // exp(-TS/TAU_SR)
  const float c1 = 0.27182818284590452f;   // e*TS/TAU_SR
  const float a2 = 0.36787944117144233f;   // exp(-TS/TAU_REF)
  const float c2 = -54.365636569180905f;   // -SCALE_REF*THETA*e*TS/TAU_REF

  float p1 = 0.f, q1 = 0.f;  // PSP filter state
  float p2 = 0.f, q2 = 0.f;  // refractory filter state

  const float* vp = v + g;
  float* op = out + (size_t)g * T_DIM;

  for (int tc = 0; tc < T_DIM / 4; ++tc) {
    float rr[4];
#pragma unroll
    for (int j = 0; j < 4; ++j) {
      const float vn = vp[(size_t)(tc * 4 + j) * BO_DIM];
      q1 = a1 * q1 + a1 * p1;
      p1 = a1 * p1 + vn;
      const float u = c1 * q1;
      q2 = a2 * q2 + a2 * p2;
      const float s = (u + c2 * q2 >= 10.0f) ? 1.0f : 0.0f;
      p2 = a2 * p2 + s;
      rr[j] = s;
    }
    const float4 r4 = make_float4(rr[0], rr[1], rr[2], rr[3]);
    *(float4*)&op[tc * 4] = r4;
  }
}

// ---------------------------------------------------------------------------
extern "C" void kernel_launch(void* const* d_in, const int* in_sizes, int n_in,
                              void* d_out, int out_size, void* d_ws, size_t ws_size,
                              hipStream_t stream) {
  const float* x = (const float*)d_in[0];  // [B, C, 1, 1, T] fp32 (binary)
  const float* W = (const float*)d_in[1];  // [O, C] fp32
  float* out = (float*)d_out;              // [B, O, 1, 1, T] fp32

  float* xt = (float*)d_ws;                  // [M, C] fp32, 65.5 MB
  float* v  = xt + (size_t)M_DIM * C_DIM;    // [M, O] fp32, 65.5 MB

  // K0: transpose to [t*B + b, c]
  dim3 g0((T_DIM + 31) / 32, C_DIM / 32, B_DIM);
  dim3 b0(32, 8);
  k_transpose<<<g0, b0, 0, stream>>>(x, xt);

  // K1: v = xt * W^T
  dim3 g1(O_DIM / 64, M_DIM / 64);
  k_gemm<<<g1, 256, 0, stream>>>(xt, W, v);

  // K2: fused filter + spike scan
  k_scan<<<BO_DIM / 256, 256, 0, stream>>>(v, out);
}

// Round 2
// 144.816 us; speedup vs baseline: 3.1706x; 3.1706x over previous
//
#include <hip/hip_runtime.h>
#include <cstddef>

// Problem constants (from reference setup_inputs)
#define T_DIM 500
#define B_DIM 32
#define C_DIM 1024
#define O_DIM 1024
#define M_DIM (T_DIM * B_DIM)   // 16000
#define BO_DIM (B_DIM * O_DIM)  // 32768

typedef __attribute__((ext_vector_type(8))) short bf16x8;
typedef __attribute__((ext_vector_type(4))) float f32x4;

static __device__ __forceinline__ ushort f2bf(float x) {
  unsigned u = __float_as_uint(x);
  return (ushort)((u + 0x7FFF + ((u >> 16) & 1)) >> 16);  // RNE
}

// ---------------------------------------------------------------------------
// K0: transpose + cast x[B, C, T] fp32 -> xt[(t*B + b), c] bf16 (row-major [M, C])
// ---------------------------------------------------------------------------
__global__ __launch_bounds__(256) void k_transpose(const float* __restrict__ x,
                                                   ushort* __restrict__ xt) {
  __shared__ float tile[32][33];
  const int b  = blockIdx.z;
  const int t0 = blockIdx.x * 32;
  const int c0 = blockIdx.y * 32;
  const int tx = threadIdx.x;      // 0..31
  const int ty = threadIdx.y;      // 0..7

  const int t = t0 + tx;
  if (t < T_DIM) {
#pragma unroll
    for (int r = 0; r < 4; ++r) {
      const int c = c0 + ty + r * 8;
      tile[ty + r * 8][tx] = x[((size_t)b * C_DIM + c) * T_DIM + t];
    }
  }
  __syncthreads();
#pragma unroll
  for (int r = 0; r < 4; ++r) {
    const int tt = t0 + ty + r * 8;
    if (tt < T_DIM) {
      xt[((size_t)tt * B_DIM + b) * C_DIM + c0 + tx] = f2bf(tile[tx][ty + r * 8]);
    }
  }
}

// ---------------------------------------------------------------------------
// KW: cast W[O, C] fp32 -> bf16
// ---------------------------------------------------------------------------
__global__ __launch_bounds__(256) void k_cast_w(const float4* __restrict__ W,
                                                ushort* __restrict__ Wb) {
  const int i = blockIdx.x * 256 + threadIdx.x;   // over O*C/4
  const float4 w = W[i];
  ushort* o = Wb + (size_t)i * 4;
  o[0] = f2bf(w.x); o[1] = f2bf(w.y); o[2] = f2bf(w.z); o[3] = f2bf(w.w);
}

// ---------------------------------------------------------------------------
// K1: bf16 MFMA GEMM (NT): v[M, O] = xt[M, K] * Wb[O, K]^T, fp32 out.
// m97 structure: 128x128 tile, BK=32, 4 waves (2x2, 64x64 each),
// global_load_lds width 16, 2 barriers per K-step, mfma_f32_16x16x32_bf16.
// Grid: 1000 linear blocks, bijective XCD chunk swizzle (1000 = 8 * 125).
// ---------------------------------------------------------------------------
__global__ __launch_bounds__(256) void k_gemm_bf16(const ushort* __restrict__ A,
                                                   const ushort* __restrict__ Bw,
                                                   float* __restrict__ C) {
  __shared__ ushort As[128 * 32];
  __shared__ ushort Bs[128 * 32];
  const int tid  = threadIdx.x;
  const int wid  = tid >> 6;       // 0..3
  const int lane = tid & 63;

  // XCD-aware chunk swizzle: XCD k owns logical tiles [k*125, (k+1)*125)
  const int lid  = blockIdx.x;            // 0..999
  const int swz  = (lid & 7) * 125 + (lid >> 3);
  const int row0 = (swz >> 3) * 128;      // 125 row tiles
  const int col0 = (swz & 7) * 128;       // 8 col tiles

  const int wr = (wid >> 1) * 64;  // wave sub-tile origin in M
  const int wc = (wid & 1) * 64;   // in N

  f32x4 acc[4][4] = {};            // acc[mi][ni]

  // staging: chunk ch covers rows ch*16..ch*16+15; lane l -> row ch*16 + l/4,
  // k-slot (l&3)*8. Wave w stages chunks w and w+4 for A and B.
  const int srow = lane >> 2;
  const int skof = (lane & 3) * 8;
  const ushort* Ag0 = A  + (size_t)(row0 + wid * 16 + srow) * C_DIM + skof;
  const ushort* Bg0 = Bw + (size_t)(col0 + wid * 16 + srow) * C_DIM + skof;
  ushort* AsP0 = &As[(wid * 16) * 32];
  ushort* AsP1 = &As[(wid * 16 + 64) * 32];
  ushort* BsP0 = &Bs[(wid * 16) * 32];
  ushort* BsP1 = &Bs[(wid * 16 + 64) * 32];

  // fragment addresses: A[m = lane&15][k = (lane>>4)*8 + j], same for B^T rows
  const int frow = lane & 15;
  const int fk   = (lane >> 4) * 8;

  for (int k0 = 0; k0 < C_DIM; k0 += 32) {
    __syncthreads();  // all waves done reading previous tile
    __builtin_amdgcn_global_load_lds(
        (const __attribute__((address_space(1))) void*)(Ag0 + k0),
        (__attribute__((address_space(3))) void*)AsP0, 16, 0, 0);
    __builtin_amdgcn_global_load_lds(
        (const __attribute__((address_space(1))) void*)(Ag0 + 64 * C_DIM + k0),
        (__attribute__((address_space(3))) void*)AsP1, 16, 0, 0);
    __builtin_amdgcn_global_load_lds(
        (const __attribute__((address_space(1))) void*)(Bg0 + k0),
        (__attribute__((address_space(3))) void*)BsP0, 16, 0, 0);
    __builtin_amdgcn_global_load_lds(
        (const __attribute__((address_space(1))) void*)(Bg0 + 64 * C_DIM + k0),
        (__attribute__((address_space(3))) void*)BsP1, 16, 0, 0);
    __syncthreads();  // compiler drains vmcnt(0) before barrier -> LDS ready

    bf16x8 af[4], bff[4];
#pragma unroll
    for (int i = 0; i < 4; ++i)
      af[i] = *(const bf16x8*)&As[(wr + i * 16 + frow) * 32 + fk];
#pragma unroll
    for (int j = 0; j < 4; ++j)
      bff[j] = *(const bf16x8*)&Bs[(wc + j * 16 + frow) * 32 + fk];
#pragma unroll
    for (int i = 0; i < 4; ++i)
#pragma unroll
      for (int j = 0; j < 4; ++j)
        acc[i][j] = __builtin_amdgcn_mfma_f32_16x16x32_bf16(af[i], bff[j], acc[i][j], 0, 0, 0);
  }

  // C/D layout: col = lane&15, row = (lane>>4)*4 + reg  [m89-verified]
  const int crow = (lane >> 4) * 4;
  const int ccol = lane & 15;
#pragma unroll
  for (int i = 0; i < 4; ++i)
#pragma unroll
    for (int j = 0; j < 4; ++j) {
      float* cp = C + (size_t)(row0 + wr + i * 16 + crow) * O_DIM + (col0 + wc + j * 16 + ccol);
#pragma unroll
      for (int r = 0; r < 4; ++r) cp[(size_t)r * O_DIM] = acc[i][j][r];
    }
}

// ---------------------------------------------------------------------------
// K2: fused PSP alpha-filter (linear, commutes with GEMM) + refractory spike
// scan. One thread per (b, o); sequential over T. v[t*BO + b*O + o].
// ---------------------------------------------------------------------------
__global__ __launch_bounds__(256) void k_scan(const float* __restrict__ v,
                                              float* __restrict__ out) {
  const int g = blockIdx.x * 256 + threadIdx.x;  // b*O + o

  const float a1 = 0.90483741803595952f;   // exp(-TS/TAU_SR)
  const float c1 = 0.27182818284590452f;   // e*TS/TAU_SR
  const float a2 = 0.36787944117144233f;   // exp(-TS/TAU_REF)
  const float c2 = -54.365636569180905f;   // -SCALE_REF*THETA*e*TS/TAU_REF

  float p1 = 0.f, q1 = 0.f;  // PSP filter state
  float p2 = 0.f, q2 = 0.f;  // refractory filter state

  const float* vp = v + g;
  float* op = out + (size_t)g * T_DIM;

  for (int tc = 0; tc < T_DIM / 4; ++tc) {
    float rr[4];
#pragma unroll
    for (int j = 0; j < 4; ++j) {
      const float vn = vp[(size_t)(tc * 4 + j) * BO_DIM];
      q1 = a1 * q1 + a1 * p1;
      p1 = a1 * p1 + vn;
      const float u = c1 * q1;
      q2 = a2 * q2 + a2 * p2;
      const float s = (u + c2 * q2 >= 10.0f) ? 1.0f : 0.0f;
      p2 = a2 * p2 + s;
      rr[j] = s;
    }
    *(float4*)&op[tc * 4] = make_float4(rr[0], rr[1], rr[2], rr[3]);
  }
}

// ---------------------------------------------------------------------------
extern "C" void kernel_launch(void* const* d_in, const int* in_sizes, int n_in,
                              void* d_out, int out_size, void* d_ws, size_t ws_size,
                              hipStream_t stream) {
  const float* x = (const float*)d_in[0];  // [B, C, 1, 1, T] fp32 (binary)
  const float* W = (const float*)d_in[1];  // [O, C] fp32
  float* out = (float*)d_out;              // [B, O, 1, 1, T] fp32

  float*  v  = (float*)d_ws;                         // [M, O] fp32, 65.5 MB
  ushort* xt = (ushort*)(v + (size_t)M_DIM * O_DIM); // [M, C] bf16, 32.8 MB
  ushort* Wb = xt + (size_t)M_DIM * C_DIM;           // [O, C] bf16, 2 MB

  // K0: transpose + cast
  dim3 g0((T_DIM + 31) / 32, C_DIM / 32, B_DIM);
  k_transpose<<<g0, dim3(32, 8), 0, stream>>>(x, xt);

  // KW: cast W to bf16
  k_cast_w<<<(O_DIM * C_DIM / 4) / 256, 256, 0, stream>>>((const float4*)W, Wb);

  // K1: v = xt * Wb^T  (bf16 MFMA, fp32 accum)
  k_gemm_bf16<<<(M_DIM / 128) * (O_DIM / 128), 256, 0, stream>>>(xt, Wb, v);

  // K2: fused filter + spike scan
  k_scan<<<BO_DIM / 256, 256, 0, stream>>>(v, out);
}

// Round 3
// 108.828 us; speedup vs baseline: 4.2191x; 1.3307x over previous
//
#include <hip/hip_runtime.h>
#include <cstddef>

// Problem constants (from reference setup_inputs)
#define T_DIM 500
#define B_DIM 32
#define C_DIM 1024
#define O_DIM 1024
#define M_DIM (T_DIM * B_DIM)   // 16000
#define BO_DIM (B_DIM * O_DIM)  // 32768

typedef __attribute__((ext_vector_type(8))) short bf16x8;
typedef __attribute__((ext_vector_type(4))) float f32x4;

static __device__ __forceinline__ ushort f2bf(float x) {
  unsigned u = __float_as_uint(x);
  return (ushort)((u + 0x7FFF + ((u >> 16) & 1)) >> 16);  // RNE
}

// ---------------------------------------------------------------------------
// K0: transpose + cast x[B, C, T] fp32 -> xt[(t*B + b), c] bf16 (row-major [M, C])
// ---------------------------------------------------------------------------
__global__ __launch_bounds__(256) void k_transpose(const float* __restrict__ x,
                                                   ushort* __restrict__ xt) {
  __shared__ float tile[32][33];
  const int b  = blockIdx.z;
  const int t0 = blockIdx.x * 32;
  const int c0 = blockIdx.y * 32;
  const int tx = threadIdx.x;      // 0..31
  const int ty = threadIdx.y;      // 0..7

  const int t = t0 + tx;
  if (t < T_DIM) {
#pragma unroll
    for (int r = 0; r < 4; ++r) {
      const int c = c0 + ty + r * 8;
      tile[ty + r * 8][tx] = x[((size_t)b * C_DIM + c) * T_DIM + t];
    }
  }
  __syncthreads();
#pragma unroll
  for (int r = 0; r < 4; ++r) {
    const int tt = t0 + ty + r * 8;
    if (tt < T_DIM) {
      xt[((size_t)tt * B_DIM + b) * C_DIM + c0 + tx] = f2bf(tile[tx][ty + r * 8]);
    }
  }
}

// ---------------------------------------------------------------------------
// KW: cast W[O, C] fp32 -> bf16
// ---------------------------------------------------------------------------
__global__ __launch_bounds__(256) void k_cast_w(const float4* __restrict__ W,
                                                ushort* __restrict__ Wb) {
  const int i = blockIdx.x * 256 + threadIdx.x;   // over O*C/4
  const float4 w = W[i];
  ushort* o = Wb + (size_t)i * 4;
  o[0] = f2bf(w.x); o[1] = f2bf(w.y); o[2] = f2bf(w.z); o[3] = f2bf(w.w);
}

// ---------------------------------------------------------------------------
// K1: bf16 MFMA GEMM (NT): v[M, O] = xt[M, K] * Wb[O, K]^T, fp32 out.
// m97 structure: 128x128 tile, BK=32, 4 waves (2x2, 64x64 each),
// global_load_lds width 16, 2 barriers per K-step, mfma_f32_16x16x32_bf16.
// Grid: 1000 linear blocks, bijective XCD chunk swizzle (1000 = 8 * 125).
// ---------------------------------------------------------------------------
__global__ __launch_bounds__(256) void k_gemm_bf16(const ushort* __restrict__ A,
                                                   const ushort* __restrict__ Bw,
                                                   float* __restrict__ C) {
  __shared__ ushort As[128 * 32];
  __shared__ ushort Bs[128 * 32];
  const int tid  = threadIdx.x;
  const int wid  = tid >> 6;       // 0..3
  const int lane = tid & 63;

  // XCD-aware chunk swizzle: XCD k owns logical tiles [k*125, (k+1)*125)
  const int lid  = blockIdx.x;            // 0..999
  const int swz  = (lid & 7) * 125 + (lid >> 3);
  const int row0 = (swz >> 3) * 128;      // 125 row tiles
  const int col0 = (swz & 7) * 128;       // 8 col tiles

  const int wr = (wid >> 1) * 64;  // wave sub-tile origin in M
  const int wc = (wid & 1) * 64;   // in N

  f32x4 acc[4][4] = {};            // acc[mi][ni]

  // staging: chunk ch covers rows ch*16..ch*16+15; lane l -> row ch*16 + l/4,
  // k-slot (l&3)*8. Wave w stages chunks w and w+4 for A and B.
  const int srow = lane >> 2;
  const int skof = (lane & 3) * 8;
  const ushort* Ag0 = A  + (size_t)(row0 + wid * 16 + srow) * C_DIM + skof;
  const ushort* Bg0 = Bw + (size_t)(col0 + wid * 16 + srow) * C_DIM + skof;
  ushort* AsP0 = &As[(wid * 16) * 32];
  ushort* AsP1 = &As[(wid * 16 + 64) * 32];
  ushort* BsP0 = &Bs[(wid * 16) * 32];
  ushort* BsP1 = &Bs[(wid * 16 + 64) * 32];

  // fragment addresses: A[m = lane&15][k = (lane>>4)*8 + j], same for B^T rows
  const int frow = lane & 15;
  const int fk   = (lane >> 4) * 8;

  for (int k0 = 0; k0 < C_DIM; k0 += 32) {
    __syncthreads();  // all waves done reading previous tile
    __builtin_amdgcn_global_load_lds(
        (const __attribute__((address_space(1))) void*)(Ag0 + k0),
        (__attribute__((address_space(3))) void*)AsP0, 16, 0, 0);
    __builtin_amdgcn_global_load_lds(
        (const __attribute__((address_space(1))) void*)(Ag0 + 64 * C_DIM + k0),
        (__attribute__((address_space(3))) void*)AsP1, 16, 0, 0);
    __builtin_amdgcn_global_load_lds(
        (const __attribute__((address_space(1))) void*)(Bg0 + k0),
        (__attribute__((address_space(3))) void*)BsP0, 16, 0, 0);
    __builtin_amdgcn_global_load_lds(
        (const __attribute__((address_space(1))) void*)(Bg0 + 64 * C_DIM + k0),
        (__attribute__((address_space(3))) void*)BsP1, 16, 0, 0);
    __syncthreads();  // compiler drains vmcnt(0) before barrier -> LDS ready

    bf16x8 af[4], bff[4];
#pragma unroll
    for (int i = 0; i < 4; ++i)
      af[i] = *(const bf16x8*)&As[(wr + i * 16 + frow) * 32 + fk];
#pragma unroll
    for (int j = 0; j < 4; ++j)
      bff[j] = *(const bf16x8*)&Bs[(wc + j * 16 + frow) * 32 + fk];
#pragma unroll
    for (int i = 0; i < 4; ++i)
#pragma unroll
      for (int j = 0; j < 4; ++j)
        acc[i][j] = __builtin_amdgcn_mfma_f32_16x16x32_bf16(af[i], bff[j], acc[i][j], 0, 0, 0);
  }

  // C/D layout: col = lane&15, row = (lane>>4)*4 + reg  [m89-verified]
  const int crow = (lane >> 4) * 4;
  const int ccol = lane & 15;
#pragma unroll
  for (int i = 0; i < 4; ++i)
#pragma unroll
    for (int j = 0; j < 4; ++j) {
      float* cp = C + (size_t)(row0 + wr + i * 16 + crow) * O_DIM + (col0 + wc + j * 16 + ccol);
#pragma unroll
      for (int r = 0; r < 4; ++r) cp[(size_t)r * O_DIM] = acc[i][j][r];
    }
}

// ---------------------------------------------------------------------------
// K2: fused PSP alpha-filter + refractory spike scan.
// One thread per (b, o); sequential over T. v[t*BO + b*O + o].
// 64-thread blocks -> 512 blocks -> all 256 CUs active (was 128 blocks).
// 3-chunk-deep register prefetch (60 t-steps lookahead) hides load latency.
// All buffer indices compile-time constant (no scratch spill).
// ---------------------------------------------------------------------------
__global__ __launch_bounds__(64) void k_scan(const float* __restrict__ v,
                                             float* __restrict__ out) {
  const int g = blockIdx.x * 64 + threadIdx.x;  // b*O + o

  const float a1 = 0.90483741803595952f;   // exp(-TS/TAU_SR)
  const float c1 = 0.27182818284590452f;   // e*TS/TAU_SR
  const float a2 = 0.36787944117144233f;   // exp(-TS/TAU_REF)
  const float c2 = -54.365636569180905f;   // -SCALE_REF*THETA*e*TS/TAU_REF

  float p1 = 0.f, q1 = 0.f;  // PSP filter state
  float p2 = 0.f, q2 = 0.f;  // refractory filter state

  const float* vp = v + g;
  float* op = out + (size_t)g * T_DIM;

  constexpr int D  = 20;   // t-steps per chunk
  constexpr int NC = 25;   // chunks (D*NC = 500)

  float b0[D], b1[D], b2[D];
#pragma unroll
  for (int j = 0; j < D; ++j) b0[j] = vp[(size_t)j * BO_DIM];
#pragma unroll
  for (int j = 0; j < D; ++j) b1[j] = vp[(size_t)(D + j) * BO_DIM];
#pragma unroll
  for (int j = 0; j < D; ++j) b2[j] = vp[(size_t)(2 * D + j) * BO_DIM];

#pragma unroll 5
  for (int c = 0; c < NC; ++c) {
    // prefetch chunk c+3 (clamped in the tail: redundant cache-hit re-loads)
    const int cn = (c + 3 < NC) ? (c + 3) : (NC - 1);
    float bn[D];
    {
      const size_t base = (size_t)cn * D;
#pragma unroll
      for (int j = 0; j < D; ++j) bn[j] = vp[(base + j) * BO_DIM];
    }

    float rr[D];
#pragma unroll
    for (int j = 0; j < D; ++j) {
      const float vn = b0[j];
      q1 = a1 * q1 + a1 * p1;
      p1 = a1 * p1 + vn;
      const float u = c1 * q1;
      q2 = a2 * q2 + a2 * p2;
      const float s = (u + c2 * q2 >= 10.0f) ? 1.0f : 0.0f;
      p2 = a2 * p2 + s;
      rr[j] = s;
    }

    float* o = op + c * D;
#pragma unroll
    for (int j = 0; j < D; j += 4)
      *(float4*)&o[j] = make_float4(rr[j], rr[j + 1], rr[j + 2], rr[j + 3]);

    // rotate the pipeline (static indices -> pure register moves / renaming)
#pragma unroll
    for (int j = 0; j < D; ++j) { b0[j] = b1[j]; b1[j] = b2[j]; b2[j] = bn[j]; }
  }
}

// ---------------------------------------------------------------------------
extern "C" void kernel_launch(void* const* d_in, const int* in_sizes, int n_in,
                              void* d_out, int out_size, void* d_ws, size_t ws_size,
                              hipStream_t stream) {
  const float* x = (const float*)d_in[0];  // [B, C, 1, 1, T] fp32 (binary)
  const float* W = (const float*)d_in[1];  // [O, C] fp32
  float* out = (float*)d_out;              // [B, O, 1, 1, T] fp32

  float*  v  = (float*)d_ws;                         // [M, O] fp32, 65.5 MB
  ushort* xt = (ushort*)(v + (size_t)M_DIM * O_DIM); // [M, C] bf16, 32.8 MB
  ushort* Wb = xt + (size_t)M_DIM * C_DIM;           // [O, C] bf16, 2 MB

  // K0: transpose + cast
  dim3 g0((T_DIM + 31) / 32, C_DIM / 32, B_DIM);
  k_transpose<<<g0, dim3(32, 8), 0, stream>>>(x, xt);

  // KW: cast W to bf16
  k_cast_w<<<(O_DIM * C_DIM / 4) / 256, 256, 0, stream>>>((const float4*)W, Wb);

  // K1: v = xt * Wb^T  (bf16 MFMA, fp32 accum)
  k_gemm_bf16<<<(M_DIM / 128) * (O_DIM / 128), 256, 0, stream>>>(xt, Wb, v);

  // K2: fused filter + spike scan
  k_scan<<<BO_DIM / 64, 64, 0, stream>>>(v, out);
}

// Round 4
// 89.980 us; speedup vs baseline: 5.1029x; 1.2095x over previous
//
#include <hip/hip_runtime.h>
#include <cstddef>

// Problem constants (from reference setup_inputs)
#define T_DIM 500
#define B_DIM 32
#define C_DIM 1024
#define O_DIM 1024
#define M_DIM (T_DIM * B_DIM)   // 16000
#define MP_DIM 16128            // padded to 63*256
#define BO_DIM (B_DIM * O_DIM)  // 32768

typedef __attribute__((ext_vector_type(8))) short bf16x8;
typedef __attribute__((ext_vector_type(4))) float f32x4;

static __device__ __forceinline__ ushort f2bf(float x) {
  unsigned u = __float_as_uint(x);
  return (ushort)((u + 0x7FFF + ((u >> 16) & 1)) >> 16);  // RNE
}
static __device__ __forceinline__ float bf2f(ushort u) {
  return __uint_as_float(((unsigned)u) << 16);
}

// ---------------------------------------------------------------------------
// K0: transpose + cast x[B, C, T] fp32 -> xt[(t*B + b), c] bf16 ([MP, C], rows
// >= 16000 never written: pad rows feed garbage into pad v rows never read)
// ---------------------------------------------------------------------------
__global__ __launch_bounds__(256) void k_transpose(const float* __restrict__ x,
                                                   ushort* __restrict__ xt) {
  __shared__ float tile[32][33];
  const int b  = blockIdx.z;
  const int t0 = blockIdx.x * 32;
  const int c0 = blockIdx.y * 32;
  const int tx = threadIdx.x;      // 0..31
  const int ty = threadIdx.y;      // 0..7

  const int t = t0 + tx;
  if (t < T_DIM) {
#pragma unroll
    for (int r = 0; r < 4; ++r) {
      const int c = c0 + ty + r * 8;
      tile[ty + r * 8][tx] = x[((size_t)b * C_DIM + c) * T_DIM + t];
    }
  }
  __syncthreads();
#pragma unroll
  for (int r = 0; r < 4; ++r) {
    const int tt = t0 + ty + r * 8;
    if (tt < T_DIM) {
      xt[((size_t)tt * B_DIM + b) * C_DIM + c0 + tx] = f2bf(tile[tx][ty + r * 8]);
    }
  }
}

// ---------------------------------------------------------------------------
// KW: cast W[O, C] fp32 -> bf16
// ---------------------------------------------------------------------------
__global__ __launch_bounds__(256) void k_cast_w(const float4* __restrict__ W,
                                                ushort* __restrict__ Wb) {
  const int i = blockIdx.x * 256 + threadIdx.x;   // over O*C/4
  const float4 w = W[i];
  ushort* o = Wb + (size_t)i * 4;
  o[0] = f2bf(w.x); o[1] = f2bf(w.y); o[2] = f2bf(w.z); o[3] = f2bf(w.w);
}

// ---------------------------------------------------------------------------
// K1: bf16 MFMA GEMM (NT): v[MP, O] = xt[MP, K] * Wb[O, K]^T, bf16 out.
// 256x256 tile, BK=64, 8 waves, 2-slot LDS ring (128 KiB), 4 phases/K-tile,
// counted vmcnt(8) (never drained in-loop), st_16x32 LDS swizzle staged via
// pre-swizzled global source, setprio around MFMA clusters.
//
// Race-freedom: ph1+ph2 perform ALL ds_reads of tile T (each wave's full frag
// set into registers); ph2 ends with lgkmcnt(0)+barrier => no wave reads the
// slot afterwards. ph3/ph4 then issue tile T+2's global_load_lds into the SAME
// slot (cannot land before issue). Tile T's loads are guaranteed landed by
// vmcnt(8)+barrier at ph1 (only tile T+1's 8 loads may be outstanding).
// ---------------------------------------------------------------------------
__global__ __launch_bounds__(512, 2) void k_gemm_bf16(const ushort* __restrict__ A,
                                                      const ushort* __restrict__ Bw,
                                                      ushort* __restrict__ C) {
  // [slot:2][mat:2(A,B)][rowhalf:2][khalf:2][r:128][k:32] bf16, swizzled k
  __shared__ ushort lds[65536];  // 128 KiB

  const int tid  = threadIdx.x;
  const int wid  = tid >> 6;       // 0..7
  const int lane = tid & 63;

  // bijective XCD chunk swizzle (m204): nwg=252, q=31, r=4
  {
  }
  const int orig = blockIdx.x;
  const int xcd  = orig & 7;
  const int base = (xcd < 4) ? xcd * 32 : 128 + (xcd - 4) * 31;
  const int wgid = base + (orig >> 3);
  const int row0 = (wgid >> 2) * 256;   // 63 row tiles (col-fast => A L2 reuse)
  const int col0 = (wgid & 3) * 256;    // 4 col tiles

  const int wm = wid >> 2;         // 0..1 : wave row-half
  const int wn = wid & 3;          // 0..3 : wave col-quarter

  f32x4 acc[8][4] = {};            // [m-frag][n-frag]

  // ---- staging source addresses (pre-swizzled k so LDS lands st_16x32) ----
  // thread thr covers LDS bytes thr*16 of each 8KB (rh,kh) chunk:
  //   r' = wid*16 + (lane>>2), k0 = (lane&3)*8; swizzle bit = (r'>>3)&1 = lane>>5
  const int srow = wid * 16 + (lane >> 2);
  const int skof = ((lane & 3) * 8) ^ (((lane >> 5) & 1) << 4);
  const ushort* Abase = A  + (size_t)(row0 + srow) * C_DIM + skof;
  const ushort* Bbase = Bw + (size_t)(col0 + srow) * C_DIM + skof;

  // ---- fragment read offsets (swizzled) ----
  const int fr  = lane & 15;
  const int fko = ((lane >> 4) * 8) ^ (((lane >> 3) & 1) << 4);
  const int aoff = wm * 8192 + fr * 32 + fko;                              // + h*4096 + i*512
  const int boff = 16384 + (wn >> 1) * 8192 + (wn & 1) * 2048 + fr * 32 + fko;  // + h*4096 + j*512

#define STAGE_A(K0S, SB)                                                          \
  _Pragma("unroll")                                                               \
  for (int rh = 0; rh < 2; ++rh)                                                  \
    _Pragma("unroll")                                                             \
    for (int kh = 0; kh < 2; ++kh)                                                \
      __builtin_amdgcn_global_load_lds(                                           \
          (const __attribute__((address_space(1))) void*)(Abase + (size_t)rh * 128 * C_DIM + (K0S) + kh * 32), \
          (__attribute__((address_space(3))) void*)&lds[(SB) + rh * 8192 + kh * 4096 + wid * 512], 16, 0, 0)

#define STAGE_B(K0S, SB)                                                          \
  _Pragma("unroll")                                                               \
  for (int rh = 0; rh < 2; ++rh)                                                  \
    _Pragma("unroll")                                                             \
    for (int kh = 0; kh < 2; ++kh)                                                \
      __builtin_amdgcn_global_load_lds(                                           \
          (const __attribute__((address_space(1))) void*)(Bbase + (size_t)rh * 128 * C_DIM + (K0S) + kh * 32), \
          (__attribute__((address_space(3))) void*)&lds[(SB) + 16384 + rh * 8192 + kh * 4096 + wid * 512], 16, 0, 0)

  // prologue: stage tiles 0 and 1
  STAGE_A(0, 0);
  STAGE_B(0, 0);
  STAGE_A(64, 32768);
  STAGE_B(64, 32768);

  for (int t = 0; t < 16; ++t) {
    const int sb = (t & 1) * 32768;
    bf16x8 a0[4][2], a1[4][2], b0[2][2], b1[2][2];

    // ---------- ph1: frags (i0-3, j0-1), MFMA quad (i0-3 x j0-1) ----------
    asm volatile("s_waitcnt vmcnt(8)" ::: "memory");   // tile t fully landed
    __builtin_amdgcn_s_barrier();                      // ...across all waves
#pragma unroll
    for (int i = 0; i < 4; ++i)
#pragma unroll
      for (int h = 0; h < 2; ++h)
        a0[i][h] = *(const bf16x8*)&lds[sb + aoff + h * 4096 + i * 512];
#pragma unroll
    for (int j = 0; j < 2; ++j)
#pragma unroll
      for (int h = 0; h < 2; ++h)
        b0[j][h] = *(const bf16x8*)&lds[sb + boff + h * 4096 + j * 512];
    asm volatile("s_waitcnt lgkmcnt(0)" ::: "memory");
    __builtin_amdgcn_sched_barrier(0);
    __builtin_amdgcn_s_setprio(1);
#pragma unroll
    for (int i = 0; i < 4; ++i)
#pragma unroll
      for (int j = 0; j < 2; ++j)
#pragma unroll
        for (int h = 0; h < 2; ++h)
          acc[i][j] = __builtin_amdgcn_mfma_f32_16x16x32_bf16(a0[i][h], b0[j][h], acc[i][j], 0, 0, 0);
    __builtin_amdgcn_s_setprio(0);
    __builtin_amdgcn_s_barrier();

    // ---------- ph2: frags (i4-7, j2-3), MFMA quad (i4-7 x j0-1) ----------
#pragma unroll
    for (int i = 0; i < 4; ++i)
#pragma unroll
      for (int h = 0; h < 2; ++h)
        a1[i][h] = *(const bf16x8*)&lds[sb + aoff + h * 4096 + (4 + i) * 512];
#pragma unroll
    for (int j = 0; j < 2; ++j)
#pragma unroll
      for (int h = 0; h < 2; ++h)
        b1[j][h] = *(const bf16x8*)&lds[sb + boff + h * 4096 + (2 + j) * 512];
    asm volatile("s_waitcnt lgkmcnt(0)" ::: "memory");
    __builtin_amdgcn_sched_barrier(0);
    __builtin_amdgcn_s_setprio(1);
#pragma unroll
    for (int i = 0; i < 4; ++i)
#pragma unroll
      for (int j = 0; j < 2; ++j)
#pragma unroll
        for (int h = 0; h < 2; ++h)
          acc[4 + i][j] = __builtin_amdgcn_mfma_f32_16x16x32_bf16(a1[i][h], b0[j][h], acc[4 + i][j], 0, 0, 0);
    __builtin_amdgcn_s_setprio(0);
    __builtin_amdgcn_s_barrier();          // ALL slot reads for tile t done

    // ---------- ph3: stage A(t+2) into this slot; MFMA (i0-3 x j2-3) ------
    if (t < 14) { STAGE_A((t + 2) * 64, sb); }
    __builtin_amdgcn_s_setprio(1);
#pragma unroll
    for (int i = 0; i < 4; ++i)
#pragma unroll
      for (int j = 0; j < 2; ++j)
#pragma unroll
        for (int h = 0; h < 2; ++h)
          acc[i][2 + j] = __builtin_amdgcn_mfma_f32_16x16x32_bf16(a0[i][h], b1[j][h], acc[i][2 + j], 0, 0, 0);
    __builtin_amdgcn_s_setprio(0);
    __builtin_amdgcn_s_barrier();

    // ---------- ph4: stage B(t+2); MFMA (i4-7 x j2-3) ---------------------
    if (t < 14) { STAGE_B((t + 2) * 64, sb); }
    __builtin_amdgcn_s_setprio(1);
#pragma unroll
    for (int i = 0; i < 4; ++i)
#pragma unroll
      for (int j = 0; j < 2; ++j)
#pragma unroll
        for (int h = 0; h < 2; ++h)
          acc[4 + i][2 + j] = __builtin_amdgcn_mfma_f32_16x16x32_bf16(a1[i][h], b1[j][h], acc[4 + i][2 + j], 0, 0, 0);
    __builtin_amdgcn_s_setprio(0);
    __builtin_amdgcn_s_barrier();
  }

  // epilogue: C/D layout col = lane&15, row = (lane>>4)*4 + reg  [m89]
  const int crow = (lane >> 4) * 4;
  const int ccol = lane & 15;
#pragma unroll
  for (int i = 0; i < 8; ++i)
#pragma unroll
    for (int j = 0; j < 4; ++j) {
      ushort* cp = C + (size_t)(row0 + wm * 128 + i * 16 + crow) * O_DIM
                     + (col0 + wn * 64 + j * 16 + ccol);
#pragma unroll
      for (int r = 0; r < 4; ++r) cp[(size_t)r * O_DIM] = f2bf(acc[i][j][r]);
    }
#undef STAGE_A
#undef STAGE_B
}

// ---------------------------------------------------------------------------
// K2: fused PSP alpha-filter + refractory spike scan (bf16 v input).
// One thread per (b, o); 64-thr blocks (512 blocks, all CUs); 3-chunk-deep
// register prefetch; static indices only.
// ---------------------------------------------------------------------------
__global__ __launch_bounds__(64) void k_scan(const ushort* __restrict__ v,
                                             float* __restrict__ out) {
  const int g = blockIdx.x * 64 + threadIdx.x;  // b*O + o

  const float a1 = 0.90483741803595952f;   // exp(-TS/TAU_SR)
  const float c1 = 0.27182818284590452f;   // e*TS/TAU_SR
  const float a2 = 0.36787944117144233f;   // exp(-TS/TAU_REF)
  const float c2 = -54.365636569180905f;   // -SCALE_REF*THETA*e*TS/TAU_REF

  float p1 = 0.f, q1 = 0.f;
  float p2 = 0.f, q2 = 0.f;

  const ushort* vp = v + g;
  float* op = out + (size_t)g * T_DIM;

  constexpr int D  = 20;   // t-steps per chunk
  constexpr int NC = 25;   // chunks (D*NC = 500)

  ushort b0[D], b1[D], b2[D];
#pragma unroll
  for (int j = 0; j < D; ++j) b0[j] = vp[(size_t)j * BO_DIM];
#pragma unroll
  for (int j = 0; j < D; ++j) b1[j] = vp[(size_t)(D + j) * BO_DIM];
#pragma unroll
  for (int j = 0; j < D; ++j) b2[j] = vp[(size_t)(2 * D + j) * BO_DIM];

#pragma unroll 5
  for (int c = 0; c < NC; ++c) {
    const int cn = (c + 3 < NC) ? (c + 3) : (NC - 1);
    ushort bn[D];
    {
      const size_t base = (size_t)cn * D;
#pragma unroll
      for (int j = 0; j < D; ++j) bn[j] = vp[(base + j) * BO_DIM];
    }

    float rr[D];
#pragma unroll
    for (int j = 0; j < D; ++j) {
      const float vn = bf2f(b0[j]);
      q1 = a1 * q1 + a1 * p1;
      p1 = a1 * p1 + vn;
      const float u = c1 * q1;
      q2 = a2 * q2 + a2 * p2;
      const float s = (u + c2 * q2 >= 10.0f) ? 1.0f : 0.0f;
      p2 = a2 * p2 + s;
      rr[j] = s;
    }

    float* o = op + c * D;
#pragma unroll
    for (int j = 0; j < D; j += 4)
      *(float4*)&o[j] = make_float4(rr[j], rr[j + 1], rr[j + 2], rr[j + 3]);

#pragma unroll
    for (int j = 0; j < D; ++j) { b0[j] = b1[j]; b1[j] = b2[j]; b2[j] = bn[j]; }
  }
}

// ---------------------------------------------------------------------------
extern "C" void kernel_launch(void* const* d_in, const int* in_sizes, int n_in,
                              void* d_out, int out_size, void* d_ws, size_t ws_size,
                              hipStream_t stream) {
  const float* x = (const float*)d_in[0];  // [B, C, 1, 1, T] fp32 (binary)
  const float* W = (const float*)d_in[1];  // [O, C] fp32
  float* out = (float*)d_out;              // [B, O, 1, 1, T] fp32

  ushort* v  = (ushort*)d_ws;                         // [MP, O] bf16, 33 MB
  ushort* xt = v + (size_t)MP_DIM * O_DIM;            // [MP, C] bf16, 33 MB
  ushort* Wb = xt + (size_t)MP_DIM * C_DIM;           // [O, C] bf16, 2 MB

  // K0: transpose + cast
  dim3 g0((T_DIM + 31) / 32, C_DIM / 32, B_DIM);
  k_transpose<<<g0, dim3(32, 8), 0, stream>>>(x, xt);

  // KW: cast W to bf16
  k_cast_w<<<(O_DIM * C_DIM / 4) / 256, 256, 0, stream>>>((const float4*)W, Wb);

  // K1: v = xt * Wb^T  (256^2 tile, 4-phase counted-vmcnt schedule)
  k_gemm_bf16<<<(MP_DIM / 256) * (O_DIM / 256), 512, 0, stream>>>(xt, Wb, v);

  // K2: fused filter + spike scan
  k_scan<<<BO_DIM / 64, 64, 0, stream>>>(v, out);
}